// Round 10
// baseline (15.445 us; speedup 1.0000x reference)
//
#include <hip/hip_runtime.h>
#include <math.h>

#define NW     21
#define EMB    256
#define TOKB   64          // tokens per block
#define LN_EPS 1e-5f

struct cpx { float re, im; };
__device__ inline cpx cmul(cpx a, cpx b){ return cpx{a.re*b.re - a.im*b.im, a.re*b.im + a.im*b.re}; }
__device__ inline cpx cadd(cpx a, cpx b){ return cpx{a.re+b.re, a.im+b.im}; }

typedef float vf4 __attribute__((ext_vector_type(4)));   // native vec for nontemporal builtin

// One G-step: (m0,m1) <- (G0*m0 + G1*m1, G2*m0 + G3*m1)
__device__ inline void gstep(const float4 a, const float4 b,
                             float& r0, float& i0, float& r1, float& i1)
{
    float nr0 = a.x*r0 - a.y*i0 + a.z*r1 - a.w*i1;
    float ni0 = a.x*i0 + a.y*r0 + a.z*i1 + a.w*r1;
    float nr1 = b.x*r0 - b.y*i0 + b.z*r1 - b.w*i1;
    float ni1 = b.x*i0 + b.y*r0 + b.z*i1 + b.w*r1;
    r0 = nr0; i0 = ni0; r1 = nr1; i1 = ni1;
}

// 256 blocks x 1024 threads (16 waves), 64 tokens/block (R7 geometry) +
// R9 micro-opts: __sincosf, tables direct from trig (one less barrier),
// paired nontemporal stores (write drain starts mid-phase-2).
//  trig   : 126 threads, one __sincosf each -> sTrig ; barrier
//  tables : sG (wires 2..19), sInit (wires 0+1), sK (wire 20) ; barrier
//  phase 1: tid<256 suffix chain e=tid -> sSt ; tid 256..383: 128 prefix
//           chains (64 tok x 2 s) -> sP4 ; barrier
//  phase 2: wave wv owns tokens wv*4..+3 in PAIRS: dot+mag, batched
//           butterfly (4 chains), epilogue, nontemporal float4 store.
__global__ __launch_bounds__(1024, 4) void qembed_one(
    const int*   __restrict__ x,
    const float* __restrict__ rp1,
    const float* __restrict__ rp2,
    const float* __restrict__ gamma,
    const float* __restrict__ beta,
    float*       __restrict__ out,
    int ntok)
{
    __shared__ float2 sTrig[2][NW][3];   // [layer][wire][kind] = (cos, sin)
    __shared__ float  sG[18][2][8];      // wires 2..19: [w-2][n][4 cpx]
    __shared__ float4 sInit[2][2][2];    // [n0][n1][s] -> (w0,w1)
    __shared__ float  sK[2][2][4];       // [s][n20] -> (K0,K1)
    __shared__ float  sSt[8][EMB];       // suffix components, component-major
    __shared__ float4 sP4[TOKB][2];      // prefix vectors per (token, s)

    const int tid      = threadIdx.x;
    const int lane     = tid & 63;
    const int wv       = tid >> 6;       // 0..15
    const int e0       = lane * 4;
    const int blockTok = blockIdx.x * TOKB;

    // hoisted global loads
    const float4 g4 = *(const float4*)(gamma + e0);
    const float4 b4 = *(const float4*)(beta  + e0);
    int pv = 0;
    if (tid >= 256 && tid < 384) {
        int idx = blockTok + ((tid - 256) >> 1);
        if (idx >= ntok) idx = ntok - 1;
        pv = x[idx];
    }

    // ---- trig: one fast sincos per thread ----
    if (tid < 126) {
        const int layer = tid / 63, r = tid % 63, w = r / 3, kind = r % 3;
        const float* rp = layer ? rp2 : rp1;
        const float p = rp[w*3+0], th = rp[w*3+1], om = rp[w*3+2];
        const float arg = (kind == 0) ? 0.5f*th
                        : (kind == 1) ? -0.5f*(p+om)
                                      : -0.5f*(p-om);
        float s, c; __sincosf(arg, &s, &c);
        sTrig[layer][w][kind] = make_float2(c, s);
    }
    __syncthreads();

    // helpers to rebuild gate constants from sTrig
    #define A_OF(w, ai) ( (ai) == 0 \
        ? cpx{sTrig[0][w][1].x * sTrig[0][w][0].x, sTrig[0][w][1].y * sTrig[0][w][0].x} \
        : cpx{sTrig[0][w][2].x * sTrig[0][w][0].y, sTrig[0][w][2].y * sTrig[0][w][0].y} )
    #define U_OF(w, n, row) ( ((n) == (row)) \
        ? ((n) == 0 ? cpx{ sTrig[1][w][1].x * sTrig[1][w][0].x,  sTrig[1][w][1].y * sTrig[1][w][0].x} \
                    : cpx{ sTrig[1][w][1].x * sTrig[1][w][0].x, -sTrig[1][w][1].y * sTrig[1][w][0].x}) \
        : ((n) == 1 ? cpx{ sTrig[1][w][2].x * sTrig[1][w][0].y,  sTrig[1][w][2].y * sTrig[1][w][0].y} \
                    : cpx{-sTrig[1][w][2].x * sTrig[1][w][0].y,  sTrig[1][w][2].y * sTrig[1][w][0].y}) )

    // ---- step-matrix tables (direct from sTrig) ----
    if (tid < 144) {
        const int w = 2 + tid/8, n = (tid >> 2) & 1, c = tid & 3;
        const int row = c >> 1;
        const int ai  = (c == 1 || c == 2) ? 1 : 0;
        cpx u = U_OF(w, n, row);
        cpx a = A_OF(w, ai);
        cpx g = cmul(u, a);
        sG[w-2][n][c*2]   = g.re;
        sG[w-2][n][c*2+1] = g.im;
    } else if (tid < 152) {
        const int idx = tid - 144;
        const int n0 = (idx >> 2) & 1, n1 = (idx >> 1) & 1, s = idx & 1;
        cpx a00 = A_OF(0, s),  a01 = A_OF(0, 1^s);
        cpx a1s = A_OF(1, s),  a1d = A_OF(1, 1^s);
        cpx u00 = U_OF(0, n0, 0), u01 = U_OF(0, n0, 1);
        cpx u10 = U_OF(1, n1, 0), u11 = U_OF(1, n1, 1);
        cpx w0 = cmul(u00, a00);
        cpx w1 = cmul(u01, a01);
        cpx t0 = cadd(cmul(w0, a1s), cmul(w1, a1d));
        cpx t1 = cadd(cmul(w0, a1d), cmul(w1, a1s));
        w0 = cmul(u10, t0);
        w1 = cmul(u11, t1);
        sInit[n0][n1][s] = make_float4(w0.re, w0.im, w1.re, w1.im);
    } else if (tid < 160) {
        const int idx = tid - 152;
        const int s = (idx >> 2) & 1, n = (idx >> 1) & 1, c = idx & 1;
        cpx u = U_OF(20, n, s);
        cpx a = A_OF(20, c ? (1^s) : s);
        cpx g = cmul(u, a);
        sK[s][n][c*2]   = g.re;
        sK[s][n][c*2+1] = g.im;
    }
    __syncthreads();

    // ---- phase 1 ----
    if (tid < 256) {
        const int e = tid;
        const int n13 = (e >> 7) & 1;
        float4 ga = *(const float4*)&sG[11][n13][0];
        float4 gb = *(const float4*)&sG[11][n13][4];
        float r00 = ga.x, i00 = ga.y, r10 = gb.x, i10 = gb.y;
        float r01 = ga.z, i01 = ga.w, r11 = gb.z, i11 = gb.w;
        #pragma unroll
        for (int i = 14; i <= 19; ++i) {
            const int ni = (e >> (20-i)) & 1;
            float4 a = *(const float4*)&sG[i-2][ni][0];
            float4 b = *(const float4*)&sG[i-2][ni][4];
            gstep(a, b, r00, i00, r10, i10);
            gstep(a, b, r01, i01, r11, i11);
        }
        const int n20 = e & 1;
        float o8[8];
        #pragma unroll
        for (int s = 0; s < 2; ++s) {
            const float4 k4 = *(const float4*)&sK[s][n20][0];
            o8[s*4+0] = k4.x*r00 - k4.y*i00 + k4.z*r10 - k4.w*i10;
            o8[s*4+1] = k4.x*i00 + k4.y*r00 + k4.z*i10 + k4.w*r10;
            o8[s*4+2] = k4.x*r01 - k4.y*i01 + k4.z*r11 - k4.w*i11;
            o8[s*4+3] = k4.x*i01 + k4.y*r01 + k4.z*i11 + k4.w*r11;
        }
        #pragma unroll
        for (int c = 0; c < 8; ++c) sSt[c][e] = o8[c];
    } else if (tid < 384) {
        const int idx = tid - 256;
        const int k = idx >> 1, s = idx & 1;
        const int v = pv;
        const int n0 = (v >> 12) & 1, n1 = (v >> 11) & 1;
        const float4 in4 = sInit[n0][n1][s];
        float r0 = in4.x, i0 = in4.y, r1 = in4.z, i1 = in4.w;
        #pragma unroll
        for (int i = 2; i <= 12; ++i) {
            const int ni = (v >> (12-i)) & 1;
            float4 a = *(const float4*)&sG[i-2][ni][0];
            float4 b = *(const float4*)&sG[i-2][ni][4];
            gstep(a, b, r0, i0, r1, i1);
        }
        sP4[k][s] = make_float4(r0, i0, r1, i1);
    }
    __syncthreads();

    // ---- phase 2: 4 tokens per wave, processed in pairs ----
    float sr[8][4];
    #pragma unroll
    for (int c = 0; c < 8; ++c) {
        float4 t = *(const float4*)&sSt[c][e0];
        sr[c][0] = t.x; sr[c][1] = t.y; sr[c][2] = t.z; sr[c][3] = t.w;
    }

    #pragma unroll
    for (int pair = 0; pair < 2; ++pair) {
        float mags[2][4];
        float ls[2], lq[2];
        #pragma unroll
        for (int t = 0; t < 2; ++t) {
            const int k = wv*4 + pair*2 + t;
            const float4 p0 = sP4[k][0];
            const float4 p1 = sP4[k][1];
            float s_ = 0.f, q_ = 0.f;
            #pragma unroll
            for (int kk = 0; kk < 4; ++kk) {
                float re = p0.x*sr[0][kk] - p0.y*sr[1][kk]
                         + p0.z*sr[2][kk] - p0.w*sr[3][kk]
                         + p1.x*sr[4][kk] - p1.y*sr[5][kk]
                         + p1.z*sr[6][kk] - p1.w*sr[7][kk];
                float im = p0.x*sr[1][kk] + p0.y*sr[0][kk]
                         + p0.z*sr[3][kk] + p0.w*sr[2][kk]
                         + p1.x*sr[5][kk] + p1.y*sr[4][kk]
                         + p1.z*sr[7][kk] + p1.w*sr[6][kk];
                const float m = __builtin_amdgcn_sqrtf(re*re + im*im);
                mags[t][kk] = m; s_ += m; q_ += m*m;
            }
            ls[t] = s_; lq[t] = q_;
        }

        #pragma unroll
        for (int off = 32; off; off >>= 1) {
            #pragma unroll
            for (int t = 0; t < 2; ++t) {
                ls[t] += __shfl_xor(ls[t], off);
                lq[t] += __shfl_xor(lq[t], off);
            }
        }

        #pragma unroll
        for (int t = 0; t < 2; ++t) {
            const int tok = blockTok + wv*4 + pair*2 + t;
            const float mu = ls[t] * (1.0f/EMB);
            float var = lq[t] * (1.0f/EMB) - mu*mu;
            if (var < 0.f) var = 0.f;
            const float rs = __builtin_amdgcn_rsqf(var + LN_EPS);
            if (tok < ntok) {
                vf4 o;
                o.x = (mags[t][0]-mu)*rs*g4.x + b4.x;
                o.y = (mags[t][1]-mu)*rs*g4.y + b4.y;
                o.z = (mags[t][2]-mu)*rs*g4.z + b4.z;
                o.w = (mags[t][3]-mu)*rs*g4.w + b4.w;
                __builtin_nontemporal_store(o, (vf4*)(out + (size_t)tok*EMB + e0));
            }
        }
    }
}

extern "C" void kernel_launch(void* const* d_in, const int* in_sizes, int n_in,
                              void* d_out, int out_size, void* d_ws, size_t ws_size,
                              hipStream_t stream) {
    const int*   x     = (const int*)  d_in[0];
    const float* rp1   = (const float*)d_in[1];
    const float* rp2   = (const float*)d_in[2];
    const float* gamma = (const float*)d_in[3];
    const float* beta  = (const float*)d_in[4];
    float* out = (float*)d_out;
    const int ntok = in_sizes[0];                    // B*S = 16384
    const int nblocks = (ntok + TOKB - 1) / TOKB;    // 256
    qembed_one<<<nblocks, 1024, 0, stream>>>(x, rp1, rp2, gamma, beta, out, ntok);
}

// Round 11
// 14.619 us; speedup vs baseline: 1.0565x; 1.0565x over previous
//
#include <hip/hip_runtime.h>
#include <math.h>

#define NW     21
#define EMB    256
#define TOKB   64          // tokens per block
#define LN_EPS 1e-5f

struct cpx { float re, im; };
__device__ inline cpx cmul(cpx a, cpx b){ return cpx{a.re*b.re - a.im*b.im, a.re*b.im + a.im*b.re}; }
__device__ inline cpx cadd(cpx a, cpx b){ return cpx{a.re+b.re, a.im+b.im}; }

// One G-step: (m0,m1) <- (G0*m0 + G1*m1, G2*m0 + G3*m1)
__device__ inline void gstep(const float4 a, const float4 b,
                             float& r0, float& i0, float& r1, float& i1)
{
    float nr0 = a.x*r0 - a.y*i0 + a.z*r1 - a.w*i1;
    float ni0 = a.x*i0 + a.y*r0 + a.z*i1 + a.w*r1;
    float nr1 = b.x*r0 - b.y*i0 + b.z*r1 - b.w*i1;
    float ni1 = b.x*i0 + b.y*r0 + b.z*i1 + b.w*r1;
    r0 = nr0; i0 = ni0; r1 = nr1; i1 = ni1;
}

// R7 configuration (empirical best, 14.59 us):
// 256 blocks x 1024 threads (16 waves), 64 tokens/block, 16 waves/CU (4/SIMD).
//  trig    : 126 threads, one sincosf each -> sTrig
//  assemble: tid<21 builds sA/sU from sTrig (cheap)
//  tables  : sG (wires 2..19), sInit (wires 0+1), sK (wire 20)
//  phase 1 : tid<256 suffix chain e=tid; tid 256..383 prefix chains (64 tok x 2 s)
//  phase 2 : wave wv handles tokens wv*4..wv*4+3; lane owns e = 4*lane..4*lane+3;
//            batched 6-level butterfly (8 chains); float4 stores.
__global__ __launch_bounds__(1024, 4) void qembed_one(
    const int*   __restrict__ x,
    const float* __restrict__ rp1,
    const float* __restrict__ rp2,
    const float* __restrict__ gamma,
    const float* __restrict__ beta,
    float*       __restrict__ out,
    int ntok)
{
    __shared__ float2 sTrig[2][NW][3];   // [layer][wire][kind] = (cos, sin)
    __shared__ cpx    sA[NW][2];
    __shared__ cpx    sU[NW][2][2];
    __shared__ float  sG[18][2][8];      // wires 2..19: [w-2][n][4 cpx]
    __shared__ float4 sInit[2][2][2];    // [n0][n1][s] -> (w0,w1)
    __shared__ float  sK[2][2][4];       // [s][n20] -> (K0,K1)
    __shared__ float  sSt[8][EMB];       // suffix components, component-major
    __shared__ float4 sP4[TOKB][2];      // prefix vectors per (token, s)

    const int tid      = threadIdx.x;
    const int lane     = tid & 63;
    const int wv       = tid >> 6;       // 0..15
    const int e0       = lane * 4;
    const int blockTok = blockIdx.x * TOKB;

    // hoisted global loads
    const float4 g4 = *(const float4*)(gamma + e0);
    const float4 b4 = *(const float4*)(beta  + e0);
    int pv = 0;
    if (tid >= 256 && tid < 384) {
        int idx = blockTok + ((tid - 256) >> 1);
        if (idx >= ntok) idx = ntok - 1;
        pv = x[idx];
    }

    // ---- trig: one sincosf per thread ----
    if (tid < 126) {
        const int layer = tid / 63, r = tid % 63, w = r / 3, kind = r % 3;
        const float* rp = layer ? rp2 : rp1;
        const float p = rp[w*3+0], th = rp[w*3+1], om = rp[w*3+2];
        const float arg = (kind == 0) ? 0.5f*th
                        : (kind == 1) ? -0.5f*(p+om)
                                      : -0.5f*(p-om);
        float s, c; sincosf(arg, &s, &c);
        sTrig[layer][w][kind] = make_float2(c, s);
    }
    __syncthreads();

    // ---- assemble gate constants ----
    if (tid < NW) {
        const int w = tid;
        float2 t0 = sTrig[0][w][0], em1 = sTrig[0][w][1], ed1 = sTrig[0][w][2];
        const float ct = t0.x, st = t0.y;
        sA[w][0] = cpx{em1.x*ct, em1.y*ct};
        sA[w][1] = cpx{ed1.x*st, ed1.y*st};
        float2 t1 = sTrig[1][w][0], em2 = sTrig[1][w][1], ed2 = sTrig[1][w][2];
        const float ct2 = t1.x, st2 = t1.y;
        sU[w][0][0] = cpx{ em2.x*ct2,  em2.y*ct2};
        sU[w][1][1] = cpx{ em2.x*ct2, -em2.y*ct2};
        sU[w][1][0] = cpx{ ed2.x*st2,  ed2.y*st2};
        sU[w][0][1] = cpx{-ed2.x*st2,  ed2.y*st2};
    }
    __syncthreads();

    // ---- step-matrix tables ----
    if (tid < 144) {
        const int w = 2 + tid/8, n = (tid >> 2) & 1, c = tid & 3;
        const int row = c >> 1;
        const int ai  = (c == 1 || c == 2) ? 1 : 0;
        cpx g = cmul(sU[w][n][row], sA[w][ai]);
        sG[w-2][n][c*2]   = g.re;
        sG[w-2][n][c*2+1] = g.im;
    } else if (tid < 152) {
        const int idx = tid - 144;
        const int n0 = (idx >> 2) & 1, n1 = (idx >> 1) & 1, s = idx & 1;
        cpx w0 = cmul(sU[0][n0][0], sA[0][s]);
        cpx w1 = cmul(sU[0][n0][1], sA[0][1^s]);
        cpx t0 = cadd(cmul(w0, sA[1][s]),   cmul(w1, sA[1][1^s]));
        cpx t1 = cadd(cmul(w0, sA[1][1^s]), cmul(w1, sA[1][s]));
        w0 = cmul(sU[1][n1][0], t0);
        w1 = cmul(sU[1][n1][1], t1);
        sInit[n0][n1][s] = make_float4(w0.re, w0.im, w1.re, w1.im);
    } else if (tid < 160) {
        const int idx = tid - 152;
        const int s = (idx >> 2) & 1, n = (idx >> 1) & 1, c = idx & 1;
        cpx g = cmul(sU[20][n][s], sA[20][c ? (1^s) : s]);
        sK[s][n][c*2]   = g.re;
        sK[s][n][c*2+1] = g.im;
    }
    __syncthreads();

    // ---- phase 1 ----
    if (tid < 256) {
        const int e = tid;
        const int n13 = (e >> 7) & 1;
        float4 ga = *(const float4*)&sG[11][n13][0];
        float4 gb = *(const float4*)&sG[11][n13][4];
        float r00 = ga.x, i00 = ga.y, r10 = gb.x, i10 = gb.y;
        float r01 = ga.z, i01 = ga.w, r11 = gb.z, i11 = gb.w;
        #pragma unroll
        for (int i = 14; i <= 19; ++i) {
            const int ni = (e >> (20-i)) & 1;
            float4 a = *(const float4*)&sG[i-2][ni][0];
            float4 b = *(const float4*)&sG[i-2][ni][4];
            gstep(a, b, r00, i00, r10, i10);
            gstep(a, b, r01, i01, r11, i11);
        }
        const int n20 = e & 1;
        float o8[8];
        #pragma unroll
        for (int s = 0; s < 2; ++s) {
            const float4 k4 = *(const float4*)&sK[s][n20][0];
            o8[s*4+0] = k4.x*r00 - k4.y*i00 + k4.z*r10 - k4.w*i10;
            o8[s*4+1] = k4.x*i00 + k4.y*r00 + k4.z*i10 + k4.w*r10;
            o8[s*4+2] = k4.x*r01 - k4.y*i01 + k4.z*r11 - k4.w*i11;
            o8[s*4+3] = k4.x*i01 + k4.y*r01 + k4.z*i11 + k4.w*r11;
        }
        #pragma unroll
        for (int c = 0; c < 8; ++c) sSt[c][e] = o8[c];
    } else if (tid < 384) {
        const int idx = tid - 256;
        const int k = idx >> 1, s = idx & 1;
        const int v = pv;
        const int n0 = (v >> 12) & 1, n1 = (v >> 11) & 1;
        const float4 in4 = sInit[n0][n1][s];
        float r0 = in4.x, i0 = in4.y, r1 = in4.z, i1 = in4.w;
        #pragma unroll
        for (int i = 2; i <= 12; ++i) {
            const int ni = (v >> (12-i)) & 1;
            float4 a = *(const float4*)&sG[i-2][ni][0];
            float4 b = *(const float4*)&sG[i-2][ni][4];
            gstep(a, b, r0, i0, r1, i1);
        }
        sP4[k][s] = make_float4(r0, i0, r1, i1);
    }
    __syncthreads();

    // ---- phase 2: 4 tokens per wave ----
    float sr[8][4];
    #pragma unroll
    for (int c = 0; c < 8; ++c) {
        float4 t = *(const float4*)&sSt[c][e0];
        sr[c][0] = t.x; sr[c][1] = t.y; sr[c][2] = t.z; sr[c][3] = t.w;
    }

    float mags[4][4];
    float ls[4], lq[4];
    #pragma unroll
    for (int t = 0; t < 4; ++t) {
        const int k = wv*4 + t;
        const float4 p0 = sP4[k][0];
        const float4 p1 = sP4[k][1];
        float s_ = 0.f, q_ = 0.f;
        #pragma unroll
        for (int kk = 0; kk < 4; ++kk) {
            float re = p0.x*sr[0][kk] - p0.y*sr[1][kk]
                     + p0.z*sr[2][kk] - p0.w*sr[3][kk]
                     + p1.x*sr[4][kk] - p1.y*sr[5][kk]
                     + p1.z*sr[6][kk] - p1.w*sr[7][kk];
            float im = p0.x*sr[1][kk] + p0.y*sr[0][kk]
                     + p0.z*sr[3][kk] + p0.w*sr[2][kk]
                     + p1.x*sr[5][kk] + p1.y*sr[4][kk]
                     + p1.z*sr[7][kk] + p1.w*sr[6][kk];
            const float m = __builtin_amdgcn_sqrtf(re*re + im*im);
            mags[t][kk] = m; s_ += m; q_ += m*m;
        }
        ls[t] = s_; lq[t] = q_;
    }

    #pragma unroll
    for (int off = 32; off; off >>= 1) {
        #pragma unroll
        for (int t = 0; t < 4; ++t) {
            ls[t] += __shfl_xor(ls[t], off);
            lq[t] += __shfl_xor(lq[t], off);
        }
    }

    #pragma unroll
    for (int t = 0; t < 4; ++t) {
        const int tok = blockTok + wv*4 + t;
        const float mu = ls[t] * (1.0f/EMB);
        float var = lq[t] * (1.0f/EMB) - mu*mu;
        if (var < 0.f) var = 0.f;
        const float rs = __builtin_amdgcn_rsqf(var + LN_EPS);
        if (tok < ntok) {
            float4 o;
            o.x = (mags[t][0]-mu)*rs*g4.x + b4.x;
            o.y = (mags[t][1]-mu)*rs*g4.y + b4.y;
            o.z = (mags[t][2]-mu)*rs*g4.z + b4.z;
            o.w = (mags[t][3]-mu)*rs*g4.w + b4.w;
            *(float4*)(out + (size_t)tok*EMB + e0) = o;
        }
    }
}

extern "C" void kernel_launch(void* const* d_in, const int* in_sizes, int n_in,
                              void* d_out, int out_size, void* d_ws, size_t ws_size,
                              hipStream_t stream) {
    const int*   x     = (const int*)  d_in[0];
    const float* rp1   = (const float*)d_in[1];
    const float* rp2   = (const float*)d_in[2];
    const float* gamma = (const float*)d_in[3];
    const float* beta  = (const float*)d_in[4];
    float* out = (float*)d_out;
    const int ntok = in_sizes[0];                    // B*S = 16384
    const int nblocks = (ntok + TOKB - 1) / TOKB;    // 256
    qembed_one<<<nblocks, 1024, 0, stream>>>(x, rp1, rp2, gamma, beta, out, ntok);
}